// Round 2
// baseline (1678.205 us; speedup 1.0000x reference)
//
#include <hip/hip_runtime.h>

typedef unsigned short u16;
typedef unsigned int u32;
typedef __attribute__((ext_vector_type(8))) short bf16x8;
typedef __attribute__((ext_vector_type(4))) float f32x4;

#define D 256
#define NODES 17
#define NBATCH 16384
#define G 6                    // batches per block
#define THREADS 512            // 8 waves
#define WELEMS 65536           // 256*256

// LDS layout (bytes)
#define LDS_AH   0             // u16 [128][256] h hi (swizzled)
#define LDS_AL   65536         // u16 [128][256] h lo (swizzled)
#define LDS_T    131072        // f32 [7][256]   per-batch S*Wl/16 term
#define LDS_PART 138240        // f32 [112][8][2] LN partials (sum, sumsq)
#define LDS_MURS 145408        // f32 [112][2]   (mu, rsqrt)
#define LDS_TOTAL 146304

__device__ __forceinline__ float bf2f(u16 u) {
  union { float f; u32 i; } v; v.i = ((u32)u) << 16; return v.f;
}
__device__ __forceinline__ u16 f2bf(float f) {
  union { float f; u32 i; } v; v.f = f;
  u32 r = v.i + 0x7fffu + ((v.i >> 16) & 1u);
  return (u16)(r >> 16);
}
// XOR swizzle: spreads row-major stride-512B rows across banks (2-way max on
// both the b128 fragment reads and the u32 staging writes). 16B-aligned
// accesses stay aligned (XOR touches bits 4-6 only).
__device__ __forceinline__ u32 swz(int row, int byteInRow) {
  return (u32)(row * 512 + (byteInRow ^ ((row & 7) << 4)));
}

// Pre-split weights: Wc = W_r - W_l/16, Wl16 = W_l/16, each into bf16 hi/lo.
// bf16x3 product (ah*bh + ah*bl + al*bh) gives ~2^-16 relative error vs fp32.
__global__ void prep_weights(const float* __restrict__ wl0, const float* __restrict__ wr0,
                             const float* __restrict__ wl1, const float* __restrict__ wr1,
                             u16* __restrict__ wc_hi, u16* __restrict__ wc_lo,
                             u16* __restrict__ wl_hi, u16* __restrict__ wl_lo) {
  int idx = blockIdx.x * 256 + threadIdx.x;      // 0 .. 131071 (2 layers)
  int layer = idx >> 16;
  int e = idx & 65535;
  const float* wl = layer ? wl1 : wl0;
  const float* wr = layer ? wr1 : wr0;
  float l16 = wl[e] * 0.0625f;                   // exact (pow2 scale)
  float wc = wr[e] - l16;
  u16 ch = f2bf(wc);
  wc_hi[idx] = ch;
  wc_lo[idx] = f2bf(wc - bf2f(ch));
  u16 lh = f2bf(l16);
  wl_hi[idx] = lh;
  wl_lo[idx] = f2bf(l16 - bf2f(lh));
}

// Fused 2-layer SAGE block. Block = G=6 batches: rows [0,102) h, [102,112)
// zero pad, [112,118) per-batch sums S, [118,128) zero pad. 8 M-tiles of 16;
// tiles 0-6 use B=Wc (h-term), tile 7 uses B=Wl16 (S-term -> T vector).
__global__ __launch_bounds__(THREADS, 2) void sage_fused(
    const float* __restrict__ x,
    const float* __restrict__ bl0, const float* __restrict__ g0, const float* __restrict__ bt0,
    const float* __restrict__ bl1, const float* __restrict__ g1, const float* __restrict__ bt1,
    const u16* __restrict__ wc_hi, const u16* __restrict__ wc_lo,
    const u16* __restrict__ wl_hi, const u16* __restrict__ wl_lo,
    float* __restrict__ out) {
  extern __shared__ __align__(16) char smem[];
  float* T = (float*)(smem + LDS_T);
  float* PART = (float*)(smem + LDS_PART);
  float* MURS = (float*)(smem + LDS_MURS);

  const int tid = threadIdx.x;
  const int wave = tid >> 6;
  const int lane = tid & 63;
  const int l15 = lane & 15;
  const int hk = lane >> 4;                 // k-group 0..3
  const int b0 = blockIdx.x * G;
  const int geff = min(G, NBATCH - b0);
  const int vrows = geff * NODES;           // valid h rows (102, tail: 68)
  const size_t gbase = (size_t)b0 * NODES * D;
  const int colA = wave * 32 + l15;         // this lane's two output cols
  const int colB = colA + 16;

  // ---- load x -> hi/lo bf16 in LDS (swizzled), zero pad rows ----
  for (int i = tid; i < vrows * 64; i += THREADS) {
    int r = i >> 6;
    int c4 = (i & 63) << 2;
    float4 v = *(const float4*)(x + gbase + (size_t)r * D + c4);
    u16 h0 = f2bf(v.x), h1 = f2bf(v.y), h2 = f2bf(v.z), h3 = f2bf(v.w);
    u16 q0 = f2bf(v.x - bf2f(h0)), q1 = f2bf(v.y - bf2f(h1));
    u16 q2 = f2bf(v.z - bf2f(h2)), q3 = f2bf(v.w - bf2f(h3));
    u32 off = swz(r, c4 * 2);
    *(uint2*)(smem + LDS_AH + off) =
        make_uint2((u32)h0 | ((u32)h1 << 16), (u32)h2 | ((u32)h3 << 16));
    *(uint2*)(smem + LDS_AL + off) =
        make_uint2((u32)q0 | ((u32)q1 << 16), (u32)q2 | ((u32)q3 << 16));
  }
  for (int i = vrows * 64 + tid; i < 128 * 64; i += THREADS) {
    int r = i >> 6;
    int c4 = (i & 63) << 2;
    u32 off = swz(r, c4 * 2);
    *(uint2*)(smem + LDS_AH + off) = make_uint2(0u, 0u);
    *(uint2*)(smem + LDS_AL + off) = make_uint2(0u, 0u);
  }
  __syncthreads();

#pragma unroll 1
  for (int layer = 0; layer < 2; ++layer) {
    const float* bl = layer ? bl1 : bl0;
    const float* lg = layer ? g1 : g0;
    const float* lb = layer ? bt1 : bt0;
    const u16* WCH = wc_hi + layer * WELEMS;
    const u16* WCL = wc_lo + layer * WELEMS;
    const u16* WLH = wl_hi + layer * WELEMS;
    const u16* WLL = wl_lo + layer * WELEMS;
    const float blA = bl[colA], blB = bl[colB];
    const float gA = lg[colA], gB = lg[colB];
    const float lbA = lb[colA], lbB = lb[colB];

    // ---- S phase: per-batch node sums -> rows 112+b (hi/lo split), u32 ----
    for (int p = tid; p < geff * 128; p += THREADS) {
      int d2 = (p & 127) << 1;              // even dim index
      int b = p >> 7;
      int rb = b * NODES;
      float s0 = 0.f, s1 = 0.f;
#pragma unroll
      for (int n = 0; n < NODES; ++n) {
        u32 off = swz(rb + n, d2 * 2);
        u32 vh = *(const u32*)(smem + LDS_AH + off);
        u32 vl = *(const u32*)(smem + LDS_AL + off);
        s0 += bf2f((u16)vh) + bf2f((u16)vl);
        s1 += bf2f((u16)(vh >> 16)) + bf2f((u16)(vl >> 16));
      }
      u16 h0 = f2bf(s0), h1 = f2bf(s1);
      u16 q0 = f2bf(s0 - bf2f(h0)), q1 = f2bf(s1 - bf2f(h1));
      u32 off = swz(112 + b, d2 * 2);
      *(u32*)(smem + LDS_AH + off) = (u32)h0 | ((u32)h1 << 16);
      *(u32*)(smem + LDS_AL + off) = (u32)q0 | ((u32)q1 << 16);
    }
    __syncthreads();

    // ---- GEMM over K=256, bf16x3 split (ah*bh + ah*bl + al*bh) ----
    f32x4 acc[7][2];
    f32x4 accS[2];
#pragma unroll
    for (int m = 0; m < 7; ++m)
#pragma unroll
      for (int nt = 0; nt < 2; ++nt) acc[m][nt] = (f32x4){0.f, 0.f, 0.f, 0.f};
    accS[0] = (f32x4){0.f, 0.f, 0.f, 0.f};
    accS[1] = (f32x4){0.f, 0.f, 0.f, 0.f};

#pragma unroll 2
    for (int k = 0; k < 8; ++k) {
      int kb = k * 32;
      // h-term: B = Wc hi/lo only (short live ranges; no selects in hot loop)
      bf16x8 bch[2], bcl[2];
#pragma unroll
      for (int nt = 0; nt < 2; ++nt) {
        size_t widx = (size_t)(colA + nt * 16) * 256 + kb + hk * 8;
        bch[nt] = *(const bf16x8*)(WCH + widx);
        bcl[nt] = *(const bf16x8*)(WCL + widx);
      }
#pragma unroll
      for (int m = 0; m < 7; ++m) {
        u32 off = swz(m * 16 + l15, kb * 2 + hk * 16);
        bf16x8 a_hi = *(const bf16x8*)(smem + LDS_AH + off);
        bf16x8 a_lo = *(const bf16x8*)(smem + LDS_AL + off);
#pragma unroll
        for (int nt = 0; nt < 2; ++nt) {
          acc[m][nt] = __builtin_amdgcn_mfma_f32_16x16x32_bf16(a_hi, bch[nt], acc[m][nt], 0, 0, 0);
          acc[m][nt] = __builtin_amdgcn_mfma_f32_16x16x32_bf16(a_hi, bcl[nt], acc[m][nt], 0, 0, 0);
          acc[m][nt] = __builtin_amdgcn_mfma_f32_16x16x32_bf16(a_lo, bch[nt], acc[m][nt], 0, 0, 0);
        }
      }
      // S-term tile (rows 112..127): B = Wl16 hi/lo
      {
        u32 off = swz(112 + l15, kb * 2 + hk * 16);
        bf16x8 a_hi = *(const bf16x8*)(smem + LDS_AH + off);
        bf16x8 a_lo = *(const bf16x8*)(smem + LDS_AL + off);
#pragma unroll
        for (int nt = 0; nt < 2; ++nt) {
          size_t widx = (size_t)(colA + nt * 16) * 256 + kb + hk * 8;
          bf16x8 bh = *(const bf16x8*)(WLH + widx);
          bf16x8 bq = *(const bf16x8*)(WLL + widx);
          accS[nt] = __builtin_amdgcn_mfma_f32_16x16x32_bf16(a_hi, bh, accS[nt], 0, 0, 0);
          accS[nt] = __builtin_amdgcn_mfma_f32_16x16x32_bf16(a_hi, bq, accS[nt], 0, 0, 0);
          accS[nt] = __builtin_amdgcn_mfma_f32_16x16x32_bf16(a_lo, bh, accS[nt], 0, 0, 0);
        }
      }
    }

    // ---- S-tile -> T (row 118 is zero-A so T[6] is exactly 0) ----
#pragma unroll
    for (int nt = 0; nt < 2; ++nt)
#pragma unroll
      for (int j = 0; j < 4; ++j) {
        int b = hk * 4 + j;                 // C/D row within tile = batch idx
        if (b < 7) T[b * 256 + colA + nt * 16] = accS[nt][j];
      }
    __syncthreads();

    // ---- c = gemm + T[batch] + b_l; LN partials (16-lane shfl groups) ----
#pragma unroll
    for (int m = 0; m < 7; ++m) {
#pragma unroll
      for (int j = 0; j < 4; ++j) {
        int r = m * 16 + hk * 4 + j;
        int b = (r * 241) >> 12;            // == r/17 for r < 102
        b = b > 6 ? 6 : b;
        float c0 = acc[m][0][j] + T[b * 256 + colA] + blA;
        float c1 = acc[m][1][j] + T[b * 256 + colB] + blB;
        acc[m][0][j] = c0;
        acc[m][1][j] = c1;
        float ss = c0 + c1;
        float qq = c0 * c0 + c1 * c1;
#pragma unroll
        for (int msk = 1; msk < 16; msk <<= 1) {  // stays within hk-group
          ss += __shfl_xor(ss, msk);
          qq += __shfl_xor(qq, msk);
        }
        if (l15 == 0) {
          PART[(r * 8 + wave) * 2] = ss;
          PART[(r * 8 + wave) * 2 + 1] = qq;
        }
      }
    }
    __syncthreads();

    if (tid < 112) {
      float ss = 0.f, qq = 0.f;
#pragma unroll
      for (int w = 0; w < 8; ++w) {
        ss += PART[(tid * 8 + w) * 2];
        qq += PART[(tid * 8 + w) * 2 + 1];
      }
      float mu = ss * 0.00390625f;
      float var = qq * 0.00390625f - mu * mu;
      MURS[tid * 2] = mu;
      MURS[tid * 2 + 1] = rsqrtf(var + 1e-5f);
    }
    __syncthreads();

    // ---- normalize + LeakyReLU + residual; LDS (L0) / global (L1) ----
#pragma unroll
    for (int m = 0; m < 7; ++m) {
#pragma unroll
      for (int j = 0; j < 4; ++j) {
        int r = m * 16 + hk * 4 + j;
        if (r < vrows) {
          float mu = MURS[r * 2];
          float rs = MURS[r * 2 + 1];
#pragma unroll
          for (int nt = 0; nt < 2; ++nt) {
            int col = colA + nt * 16;
            float y = (acc[m][nt][j] - mu) * rs * (nt ? gB : gA) + (nt ? lbB : lbA);
            float av = y > 0.f ? y : 0.01f * y;
            u32 off = swz(r, col * 2);
            float hold = bf2f(*(const u16*)(smem + LDS_AH + off)) +
                         bf2f(*(const u16*)(smem + LDS_AL + off));
            float o = av + hold;
            if (layer == 0) {
              u16 oh = f2bf(o);
              *(u16*)(smem + LDS_AH + off) = oh;
              *(u16*)(smem + LDS_AL + off) = f2bf(o - bf2f(oh));
            } else {
              out[gbase + (size_t)r * D + col] = o;
            }
          }
        }
      }
    }
    __syncthreads();
  }
}

extern "C" void kernel_launch(void* const* d_in, const int* in_sizes, int n_in,
                              void* d_out, int out_size, void* d_ws, size_t ws_size,
                              hipStream_t stream) {
  const float* x   = (const float*)d_in[0];
  const float* wl0 = (const float*)d_in[1];
  const float* bl0 = (const float*)d_in[2];
  const float* wr0 = (const float*)d_in[3];
  const float* g0  = (const float*)d_in[4];
  const float* bt0 = (const float*)d_in[5];
  const float* wl1 = (const float*)d_in[6];
  const float* bl1 = (const float*)d_in[7];
  const float* wr1 = (const float*)d_in[8];
  const float* g1  = (const float*)d_in[9];
  const float* bt1 = (const float*)d_in[10];

  u16* ws = (u16*)d_ws;                 // 1 MiB used: 4 arrays x [2][256][256] u16
  u16* wch = ws;
  u16* wcl = ws + 2 * WELEMS;
  u16* wlh = ws + 4 * WELEMS;
  u16* wll = ws + 6 * WELEMS;

  prep_weights<<<512, 256, 0, stream>>>(wl0, wr0, wl1, wr1, wch, wcl, wlh, wll);

  hipFuncSetAttribute((const void*)sage_fused,
                      hipFuncAttributeMaxDynamicSharedMemorySize, LDS_TOTAL);
  int grid = (NBATCH + G - 1) / G;      // 2731
  sage_fused<<<grid, THREADS, LDS_TOTAL, stream>>>(
      x, bl0, g0, bt0, bl1, g1, bt1, wch, wcl, wlh, wll, (float*)d_out);
}